// Round 5
// baseline (926.679 us; speedup 1.0000x reference)
//
#include <hip/hip_runtime.h>

// ---------------------------------------------------------------------------
// AttentionBlock: out = softmax((xWq^T)(xWk^T)^T / sqrt(512)) (xWv^T)
// R4: attn = R1 phasing (QBLK=32, KVBLK=32, 3 syncthreads/iter, 2 blk/CU) but
//     8 waves with (d-quarter x kv-half) QK split, partial-S via LDS f32
//     atomics (kills K-read dup), e-split-8 PV. VGPR ~105 -> 16 waves/CU.
// ---------------------------------------------------------------------------

typedef __bf16 bf16x8 __attribute__((ext_vector_type(8)));
typedef __bf16 bf16x4 __attribute__((ext_vector_type(4)));
typedef float  f32x4  __attribute__((ext_vector_type(4)));

constexpr int SEQ = 2048;
constexpr int DM  = 512;
constexpr int NB  = 8;
constexpr int GS  = NB * SEQ;    // 16384
constexpr int NT2 = SEQ / 32;    // 64 kv tiles of 32

__device__ __forceinline__ void gl16(const void* g, void* l) {
  __builtin_amdgcn_global_load_lds((const __attribute__((address_space(1))) void*)g,
                                   (__attribute__((address_space(3))) void*)l, 16, 0, 0);
}

__device__ __forceinline__ f32x4 mfma16(bf16x8 a, bf16x8 b, f32x4 c) {
  return __builtin_amdgcn_mfma_f32_16x16x32_bf16(a, b, c, 0, 0, 0);
}

// ---------------------------------------------------------------------------
// Kernel 0: fp32 -> bf16 conversion; Wq scaled by log2(e)/sqrt(512).
// ---------------------------------------------------------------------------
__global__ void convert_kernel(const float* __restrict__ x,
                               const float* __restrict__ wq,
                               const float* __restrict__ wk,
                               const float* __restrict__ wv,
                               __bf16* __restrict__ xb,
                               __bf16* __restrict__ wqb,
                               __bf16* __restrict__ wkb,
                               __bf16* __restrict__ wvb) {
  const int NX4 = (GS * DM) / 4;
  const int NW4 = (DM * DM) / 4;
  const float SCL = 0.0637639022f;  // log2(e)/sqrt(512)
  const int stride = gridDim.x * blockDim.x;
  const int tid = blockIdx.x * blockDim.x + threadIdx.x;
  for (int i = tid; i < NX4; i += stride) {
    float4 v = ((const float4*)x)[i];
    bf16x4 o = { (__bf16)v.x, (__bf16)v.y, (__bf16)v.z, (__bf16)v.w };
    ((bf16x4*)xb)[i] = o;
  }
  for (int i = tid; i < NW4; i += stride) {
    float4 v = ((const float4*)wq)[i];
    bf16x4 o = { (__bf16)(v.x * SCL), (__bf16)(v.y * SCL),
                 (__bf16)(v.z * SCL), (__bf16)(v.w * SCL) };
    ((bf16x4*)wqb)[i] = o;
  }
  for (int i = tid; i < NW4; i += stride) {
    float4 v = ((const float4*)wk)[i];
    bf16x4 o = { (__bf16)v.x, (__bf16)v.y, (__bf16)v.z, (__bf16)v.w };
    ((bf16x4*)wkb)[i] = o;
  }
  for (int i = tid; i < NW4; i += stride) {
    float4 v = ((const float4*)wv)[i];
    bf16x4 o = { (__bf16)v.x, (__bf16)v.y, (__bf16)v.z, (__bf16)v.w };
    ((bf16x4*)wvb)[i] = o;
  }
}

// ---------------------------------------------------------------------------
// Kernel 1: NT GEMM  C[M][N] = A[M][512] * B[N][512]^T   (bf16 in, bf16 out)
// ---------------------------------------------------------------------------
__global__ __launch_bounds__(256, 2) void gemm_nt_kernel(
    const __bf16* __restrict__ A, const __bf16* __restrict__ Bm,
    __bf16* __restrict__ C, int N) {
  __shared__ __bf16 As[128 * 32];
  __shared__ __bf16 Bs[128 * 32];
  const int t = threadIdx.x;
  const int w = t >> 6, l = t & 63;
  const int l15 = l & 15, lg = l >> 4;
  const int m0 = blockIdx.x * 128, n0 = blockIdx.y * 128;
  const int wr = w >> 1, wc = w & 1;

  f32x4 acc[4][4] = {};
  const char* Ab = (const char*)A + (size_t)m0 * (DM * 2);
  const char* Bb = (const char*)Bm + (size_t)n0 * (DM * 2);

  for (int k0 = 0; k0 < DM; k0 += 32) {
#pragma unroll
    for (int i = 0; i < 2; ++i) {
      const int f = (i * 256 + t) * 16;
      const int row = f >> 6, c = f & 63;
      gl16(Ab + (size_t)row * (DM * 2) + k0 * 2 + c, (char*)As + f);
      gl16(Bb + (size_t)row * (DM * 2) + k0 * 2 + c, (char*)Bs + f);
    }
    __syncthreads();
    bf16x8 af[4], bfr[4];
#pragma unroll
    for (int mi = 0; mi < 4; ++mi)
      af[mi] = *(const bf16x8*)((const char*)As + (wr * 64 + mi * 16 + l15) * 64 + lg * 16);
#pragma unroll
    for (int ni = 0; ni < 4; ++ni)
      bfr[ni] = *(const bf16x8*)((const char*)Bs + (wc * 64 + ni * 16 + l15) * 64 + lg * 16);
#pragma unroll
    for (int mi = 0; mi < 4; ++mi)
#pragma unroll
      for (int ni = 0; ni < 4; ++ni)
        acc[mi][ni] = mfma16(af[mi], bfr[ni], acc[mi][ni]);
    __syncthreads();
  }
#pragma unroll
  for (int mi = 0; mi < 4; ++mi)
#pragma unroll
    for (int ni = 0; ni < 4; ++ni)
#pragma unroll
      for (int r = 0; r < 4; ++r) {
        const int row = m0 + wr * 64 + mi * 16 + lg * 4 + r;
        const int col = n0 + wc * 64 + ni * 16 + l15;
        C[(size_t)row * N + col] = (__bf16)acc[mi][ni][r];
      }
}

// ---------------------------------------------------------------------------
// Kernel 2: fused flash attention (R4).
// Grid 512 blocks; b = bid&7 (XCD-matched), q0 = (bid>>3)*32. 512 thr/8 waves.
// QK^T: wave w -> dh=w&3 (d-slice 128), kj=w>>2 (16 kv); partial S summed by
//       ds_add_f32 atomics into Sa[32][34] (pre-zeroed; re-zeroed in softmax).
// PV:   wave w -> e columns [w*64, w*64+64), o[2][4] (32 VGPR).
// LDS: Ks[32][512] swz(row&7), Vs[512][32] swz(e&3), Sa, Ps swz(row&3).
// 70.7KB -> 2 blk/CU; ~105 VGPR -> 16 waves/CU.
// ---------------------------------------------------------------------------
__global__ __launch_bounds__(512, 4) void attn_kernel(
    const __bf16* __restrict__ QK, const __bf16* __restrict__ Vt,
    float* __restrict__ Out) {
  __shared__ __align__(16) __bf16 Ks[32 * 512];
  __shared__ __align__(16) __bf16 Vs[512 * 32];
  __shared__ float  Sa[32 * 34];
  __shared__ __bf16 Ps[32 * 32];
  __shared__ float  m_s[32], l_s[32], corr_s[32];
  __shared__ int    flags_s[8];

  const int t = threadIdx.x;
  const int w = t >> 6, l = t & 63;
  const int l15 = l & 15, lg = l >> 4;
  const int b = blockIdx.x & 7;
  const int q0 = (blockIdx.x >> 3) * 32;
  const int dh = w & 3;        // d-quarter for QK^T
  const int kj = w >> 2;       // kv half for QK^T

  char* KsB = (char*)Ks;
  char* VsB = (char*)Vs;
  const char* Kb = (const char*)QK + (size_t)b * SEQ * 2048 + 1024;  // K cols
  const char* Vb = (const char*)Vt + (size_t)b * SEQ * 2;

  // ---- precomputed staging offsets (loop-invariant) ----
  // K: round i covers rows i*8..i*8+7; thread -> row i*8+w, 16B chunk l.
  const int krow_sw = (w & 7) << 4;
  const int ksrc0 = w * 2048 + ((l * 16) ^ krow_sw);     // + i*8*2048 + kv0*2048
  // V: round i covers e = i*128 + (t>>2); slot t&3.
  const int ve = t >> 2;
  const int vsrc0 = (((t & 3) << 4) ^ ((ve & 3) << 4));  // + e*GS*2 + kv0*2
  const int vdst0 = ve * 64 + ((t & 3) << 4);            // linear == f = t*16 within round

  // ---- Q fragments: rows q0+mi*16+l15, d = dh*128 + ks*32 + lg*8 .. ----
  bf16x8 qf[2][4];
  {
    const char* Qp = (const char*)QK + (size_t)(b * SEQ + q0 + l15) * 2048 +
                     dh * 256 + lg * 16;
#pragma unroll
    for (int mi = 0; mi < 2; ++mi)
#pragma unroll
      for (int ks = 0; ks < 4; ++ks)
        qf[mi][ks] = *(const bf16x8*)(Qp + (size_t)mi * 16 * 2048 + ks * 64);
  }

  f32x4 o[2][4] = {};

  // ---- prologue: zero Sa, init stats, stage K tile 0 ----
  for (int idx = t; idx < 32 * 34; idx += 512) Sa[idx] = 0.f;
  if (t < 32) { m_s[t] = -__builtin_inff(); l_s[t] = 0.f; }
#pragma unroll
  for (int i = 0; i < 4; ++i)
    gl16(Kb + i * 8 * 2048 + ksrc0, KsB + (i * 512 + t) * 16);
  __syncthreads();

  for (int it = 0; it < NT2; ++it) {
    const size_t kv0 = (size_t)it * 32;

    // ---- phase A: issue V[it] stage; QK^T partials -> Sa atomics ----
#pragma unroll
    for (int i = 0; i < 4; ++i)
      gl16(Vb + kv0 * 2 + (size_t)(i * 128 + ve) * (GS * 2) + vsrc0,
           VsB + i * 8192 + vdst0);
    {
      f32x4 s0 = {}, s1 = {};
      const char* KsR = KsB + (kj * 16 + l15) * 1024;
      const int ksw = (l15 & 7) << 4;
      __builtin_amdgcn_s_setprio(1);
#pragma unroll
      for (int ks = 0; ks < 4; ++ks) {
        bf16x8 kf = *(const bf16x8*)(KsR + ((dh * 256 + ks * 64 + lg * 16) ^ ksw));
        s0 = mfma16(qf[0][ks], kf, s0);
        s1 = mfma16(qf[1][ks], kf, s1);
      }
      __builtin_amdgcn_s_setprio(0);
      const int scol = kj * 16 + l15;
#pragma unroll
      for (int r = 0; r < 4; ++r) {
        atomicAdd(&Sa[(lg * 4 + r) * 34 + scol], s0[r]);
        atomicAdd(&Sa[(16 + lg * 4 + r) * 34 + scol], s1[r]);
      }
    }
    __syncthreads();

    // ---- phase B: softmax (512 thr, 2 scores each), re-zero Sa ----
    {
      const int row = t >> 4, c = t & 15;
      float a0 = Sa[row * 34 + 2 * c];
      float a1 = Sa[row * 34 + 2 * c + 1];
      Sa[row * 34 + 2 * c] = 0.f;
      Sa[row * 34 + 2 * c + 1] = 0.f;
      float tmax = fmaxf(a0, a1);
      tmax = fmaxf(tmax, __shfl_xor(tmax, 1));
      tmax = fmaxf(tmax, __shfl_xor(tmax, 2));
      tmax = fmaxf(tmax, __shfl_xor(tmax, 4));
      tmax = fmaxf(tmax, __shfl_xor(tmax, 8));
      const float mold = m_s[row];
      const float mnew = fmaxf(mold, tmax);
      const float corr = exp2f(mold - mnew);   // exactly 1.0f when no new max
      const float p0 = exp2f(a0 - mnew), p1 = exp2f(a1 - mnew);
      float rsum = p0 + p1;
      rsum += __shfl_xor(rsum, 1);
      rsum += __shfl_xor(rsum, 2);
      rsum += __shfl_xor(rsum, 4);
      rsum += __shfl_xor(rsum, 8);
      if (c == 0) { m_s[row] = mnew; l_s[row] = l_s[row] * corr + rsum; corr_s[row] = corr; }
      const int allskip = __all(corr == 1.0f);
      if (l == 0) flags_s[w] = allskip;
      // P write: kv=2c,2c+1 -> u32 at swizzled slot
      unsigned short u0 = __builtin_bit_cast(unsigned short, (__bf16)p0);
      unsigned short u1 = __builtin_bit_cast(unsigned short, (__bf16)p1);
      unsigned int pp = (unsigned int)u0 | ((unsigned int)u1 << 16);
      *(unsigned int*)((char*)Ps + row * 64 + (((c >> 2) ^ (row & 3)) << 4) +
                       (c & 3) * 4) = pp;
    }
    __syncthreads();

    // ---- phase C: issue K[it+1]; rescale o; PV ----
    {
      const size_t kvn = (size_t)((it + 1) & (NT2 - 1)) * 32;
#pragma unroll
      for (int i = 0; i < 4; ++i)
        gl16(Kb + (kvn + i * 8) * 2048 + ksrc0, KsB + (i * 512 + t) * 16);

      int fl = 1;
#pragma unroll
      for (int i = 0; i < 8; ++i) fl &= flags_s[i];
      if (!fl) {
#pragma unroll
        for (int mi = 0; mi < 2; ++mi) {
          float cr[4];
#pragma unroll
          for (int r = 0; r < 4; ++r) cr[r] = corr_s[mi * 16 + lg * 4 + r];
#pragma unroll
          for (int ni = 0; ni < 4; ++ni)
#pragma unroll
            for (int r = 0; r < 4; ++r) o[mi][ni][r] *= cr[r];
        }
      }
      bf16x8 pf[2];
#pragma unroll
      for (int mi = 0; mi < 2; ++mi) {
        const int prow = mi * 16 + l15;
        pf[mi] = *(const bf16x8*)((const char*)Ps + prow * 64 +
                                  ((lg ^ (prow & 3)) << 4));
      }
      __builtin_amdgcn_s_setprio(1);
#pragma unroll
      for (int ni = 0; ni < 4; ++ni) {
        const int er = w * 64 + ni * 16 + l15;
        bf16x8 vf = *(const bf16x8*)((const char*)Vs + er * 64 +
                                     ((lg ^ (er & 3)) << 4));
#pragma unroll
        for (int mi = 0; mi < 2; ++mi)
          o[mi][ni] = mfma16(pf[mi], vf, o[mi][ni]);
      }
      __builtin_amdgcn_s_setprio(0);
    }
    __syncthreads();
  }

  // ---- epilogue: normalize, write fp32 ----
#pragma unroll
  for (int mi = 0; mi < 2; ++mi) {
    float rl[4];
#pragma unroll
    for (int r = 0; r < 4; ++r) rl[r] = 1.0f / l_s[mi * 16 + lg * 4 + r];
#pragma unroll
    for (int ni = 0; ni < 4; ++ni)
#pragma unroll
      for (int r = 0; r < 4; ++r) {
        const int row = q0 + mi * 16 + lg * 4 + r;
        const int col = w * 64 + ni * 16 + l15;
        Out[((size_t)b * SEQ + row) * DM + col] = o[mi][ni][r] * rl[r];
      }
  }
}

// ---------------------------------------------------------------------------
// Launcher. Workspace (bytes, total 68,681,728):
//   xb 0 | wqkb 16777216 (Wq*SCL;Wk) | wvb 17825792 | qk 18350080
//   ([16384][1024]: Q cols 0..511, K cols 512..1023) | vt 51904512
// ---------------------------------------------------------------------------
extern "C" void kernel_launch(void* const* d_in, const int* in_sizes, int n_in,
                              void* d_out, int out_size, void* d_ws, size_t ws_size,
                              hipStream_t stream) {
  const float* x  = (const float*)d_in[0];
  const float* wq = (const float*)d_in[1];
  const float* wk = (const float*)d_in[2];
  const float* wv = (const float*)d_in[3];
  float* out = (float*)d_out;
  char* ws = (char*)d_ws;

  __bf16* xb   = (__bf16*)(ws);
  __bf16* wqkb = (__bf16*)(ws + 16777216);
  __bf16* wvb  = (__bf16*)(ws + 17825792);
  __bf16* qk   = (__bf16*)(ws + 18350080);
  __bf16* vt   = (__bf16*)(ws + 51904512);

  convert_kernel<<<2048, 256, 0, stream>>>(x, wq, wk, wv,
                                           xb, wqkb, wqkb + 262144, wvb);
  // [Q|K] = x * [Wq*SCL;Wk]^T : [16384x1024]
  gemm_nt_kernel<<<dim3(GS / 128, 1024 / 128), 256, 0, stream>>>(xb, wqkb, qk, 1024);
  // Vt[e][gs] = Wv * x^T : [512x16384]
  gemm_nt_kernel<<<dim3(DM / 128, GS / 128), 256, 0, stream>>>(wvb, xb, vt, GS);
  // fused attention
  attn_kernel<<<512, 512, 0, stream>>>(qk, vt, out);
}

// Round 6
// 325.271 us; speedup vs baseline: 2.8489x; 2.8489x over previous
//
#include <hip/hip_runtime.h>

// ---------------------------------------------------------------------------
// AttentionBlock: out = softmax((xWq^T)(xWk^T)^T / sqrt(512)) (xWv^T)
// R5 = R1 structure (QBLK=32, 4 waves, 3 phases, 2 blk/CU) with:
//   - KVBLK=64 (Ks 64KB single-buffer; K-stage issued at phase-B start,
//     lgkm-only barriers at A/B ends, vmcnt(0) only at C end)
//   - V read global->VGPR directly (perfectly coalesced B-frags; no V LDS)
//   - e-split PV: wave owns 128 e-cols, o[2][8]; V loads in 2 batches
// ---------------------------------------------------------------------------

typedef __bf16 bf16x8 __attribute__((ext_vector_type(8)));
typedef __bf16 bf16x4 __attribute__((ext_vector_type(4)));
typedef float  f32x4  __attribute__((ext_vector_type(4)));

constexpr int SEQ = 2048;
constexpr int DM  = 512;
constexpr int NB  = 8;
constexpr int GS  = NB * SEQ;    // 16384
constexpr int NT  = SEQ / 64;    // 32 kv tiles of 64

__device__ __forceinline__ void gl16(const void* g, void* l) {
  __builtin_amdgcn_global_load_lds((const __attribute__((address_space(1))) void*)g,
                                   (__attribute__((address_space(3))) void*)l, 16, 0, 0);
}

__device__ __forceinline__ f32x4 mfma16(bf16x8 a, bf16x8 b, f32x4 c) {
  return __builtin_amdgcn_mfma_f32_16x16x32_bf16(a, b, c, 0, 0, 0);
}

// ---------------------------------------------------------------------------
// Kernel 0: fp32 -> bf16 conversion; Wq scaled by log2(e)/sqrt(512).
// ---------------------------------------------------------------------------
__global__ void convert_kernel(const float* __restrict__ x,
                               const float* __restrict__ wq,
                               const float* __restrict__ wk,
                               const float* __restrict__ wv,
                               __bf16* __restrict__ xb,
                               __bf16* __restrict__ wqb,
                               __bf16* __restrict__ wkb,
                               __bf16* __restrict__ wvb) {
  const int NX4 = (GS * DM) / 4;
  const int NW4 = (DM * DM) / 4;
  const float SCL = 0.0637639022f;  // log2(e)/sqrt(512)
  const int stride = gridDim.x * blockDim.x;
  const int tid = blockIdx.x * blockDim.x + threadIdx.x;
  for (int i = tid; i < NX4; i += stride) {
    float4 v = ((const float4*)x)[i];
    bf16x4 o = { (__bf16)v.x, (__bf16)v.y, (__bf16)v.z, (__bf16)v.w };
    ((bf16x4*)xb)[i] = o;
  }
  for (int i = tid; i < NW4; i += stride) {
    float4 v = ((const float4*)wq)[i];
    bf16x4 o = { (__bf16)(v.x * SCL), (__bf16)(v.y * SCL),
                 (__bf16)(v.z * SCL), (__bf16)(v.w * SCL) };
    ((bf16x4*)wqb)[i] = o;
  }
  for (int i = tid; i < NW4; i += stride) {
    float4 v = ((const float4*)wk)[i];
    bf16x4 o = { (__bf16)v.x, (__bf16)v.y, (__bf16)v.z, (__bf16)v.w };
    ((bf16x4*)wkb)[i] = o;
  }
  for (int i = tid; i < NW4; i += stride) {
    float4 v = ((const float4*)wv)[i];
    bf16x4 o = { (__bf16)v.x, (__bf16)v.y, (__bf16)v.z, (__bf16)v.w };
    ((bf16x4*)wvb)[i] = o;
  }
}

// ---------------------------------------------------------------------------
// Kernel 1: NT GEMM  C[M][N] = A[M][512] * B[N][512]^T   (bf16 in, bf16 out)
// ---------------------------------------------------------------------------
__global__ __launch_bounds__(256, 2) void gemm_nt_kernel(
    const __bf16* __restrict__ A, const __bf16* __restrict__ Bm,
    __bf16* __restrict__ C, int N) {
  __shared__ __bf16 As[128 * 32];
  __shared__ __bf16 Bs[128 * 32];
  const int t = threadIdx.x;
  const int w = t >> 6, l = t & 63;
  const int l15 = l & 15, lg = l >> 4;
  const int m0 = blockIdx.x * 128, n0 = blockIdx.y * 128;
  const int wr = w >> 1, wc = w & 1;

  f32x4 acc[4][4] = {};
  const char* Ab = (const char*)A + (size_t)m0 * (DM * 2);
  const char* Bb = (const char*)Bm + (size_t)n0 * (DM * 2);

  for (int k0 = 0; k0 < DM; k0 += 32) {
#pragma unroll
    for (int i = 0; i < 2; ++i) {
      const int f = (i * 256 + t) * 16;
      const int row = f >> 6, c = f & 63;
      gl16(Ab + (size_t)row * (DM * 2) + k0 * 2 + c, (char*)As + f);
      gl16(Bb + (size_t)row * (DM * 2) + k0 * 2 + c, (char*)Bs + f);
    }
    __syncthreads();
    bf16x8 af[4], bfr[4];
#pragma unroll
    for (int mi = 0; mi < 4; ++mi)
      af[mi] = *(const bf16x8*)((const char*)As + (wr * 64 + mi * 16 + l15) * 64 + lg * 16);
#pragma unroll
    for (int ni = 0; ni < 4; ++ni)
      bfr[ni] = *(const bf16x8*)((const char*)Bs + (wc * 64 + ni * 16 + l15) * 64 + lg * 16);
#pragma unroll
    for (int mi = 0; mi < 4; ++mi)
#pragma unroll
      for (int ni = 0; ni < 4; ++ni)
        acc[mi][ni] = mfma16(af[mi], bfr[ni], acc[mi][ni]);
    __syncthreads();
  }
#pragma unroll
  for (int mi = 0; mi < 4; ++mi)
#pragma unroll
    for (int ni = 0; ni < 4; ++ni)
#pragma unroll
      for (int r = 0; r < 4; ++r) {
        const int row = m0 + wr * 64 + mi * 16 + lg * 4 + r;
        const int col = n0 + wc * 64 + ni * 16 + l15;
        C[(size_t)row * N + col] = (__bf16)acc[mi][ni][r];
      }
}

// ---------------------------------------------------------------------------
// Kernel 2: fused flash attention (R5).
// Grid 512 blocks; b = bid&7 (XCD-matched), q0 = (bid>>3)*32. 256 thr/4 waves.
// Per iter (KVBLK=64), 3 phases:
//  A: issue V e-lower loads (global->reg); QK^T (wave=(qi 16q, kj 32kv),
//     Q in regs, K from LDS) -> Ss. [lgkm barrier]
//  B: issue K[it+1] stage (16 gl16); softmax 32x64 (8 thr/row) -> Ps, stats.
//     [lgkm barrier]
//  C: rescale o; pf reads; PV e-lower; issue+PV e-upper (V global B-frags,
//     64B-coalesced). [vmcnt(0)+lgkm barrier]
// LDS: Ks[64][512] swz (64KB) + Ss[32][68] f32 + Ps[32][64] swz + stats
//      = 76.9KB -> 2 blk/CU. No V in LDS.
// ---------------------------------------------------------------------------
__global__ __launch_bounds__(256, 2) void attn_kernel(
    const __bf16* __restrict__ QK, const __bf16* __restrict__ Vt,
    float* __restrict__ Out) {
  __shared__ __align__(16) __bf16 Ks[64 * 512];
  __shared__ float  Ss[32 * 68];
  __shared__ __align__(16) __bf16 Ps[32 * 64];
  __shared__ float  m_s[32], l_s[32], corr_s[32];
  __shared__ int    flags_s[4];

  const int t = threadIdx.x;
  const int w = t >> 6, l = t & 63;
  const int l15 = l & 15, lg = l >> 4;
  const int b = blockIdx.x & 7;            // batch == XCD
  const int q0 = (blockIdx.x >> 3) * 32;
  const int qi = w >> 1, kj = w & 1;

  char* KsB = (char*)Ks;
  const char* Kb = (const char*)QK + (size_t)b * SEQ * 2048 + 1024;  // K cols
  const char* Vb = (const char*)Vt + (size_t)b * SEQ * 2;            // Vt[e][b*SEQ+s]

  // Q fragments: rows q0+qi*16+l15, full D=512 (64 VGPR)
  bf16x8 qf[16];
  {
    const char* Qp = (const char*)QK + (size_t)(b * SEQ + q0 + qi * 16 + l15) * 2048 + lg * 16;
#pragma unroll
    for (int ks = 0; ks < 16; ++ks)
      qf[ks] = *(const bf16x8*)(Qp + ks * 64);
  }

  f32x4 o[2][8] = {};
  if (t < 32) { m_s[t] = -__builtin_inff(); l_s[t] = 0.f; }

  // K staging: f=(i*256+t)*16 -> row=f>>10, col=f&1023; source pre-swizzled.
#pragma unroll
  for (int i = 0; i < 16; ++i) {
    const int f = (i * 256 + t) * 16;
    const int row = f >> 10, c = f & 1023;
    gl16(Kb + (size_t)row * 2048 + (c ^ ((row & 7) << 4)), KsB + f);
  }
  __syncthreads();

  // loop-invariant read offsets
  const int kswz = (l15 & 7) << 4;
  const char* KsR0 = KsB + (kj * 32 + l15) * 1024;       // kv cols kj*32+0..15
  const char* KsR1 = KsR0 + 16 * 1024;                   // kv cols kj*32+16..31
  const size_t vstep = (size_t)GS * 2;                   // Vt row stride

  for (int it = 0; it < NT; ++it) {
    const size_t kv0 = (size_t)it * 64;

    // ---- phase A: issue V e-lower (wave e-slice w*128 + [0,64)) ----
    bf16x8 vfA[4][2];
#pragma unroll
    for (int ni = 0; ni < 4; ++ni)
#pragma unroll
      for (int ks = 0; ks < 2; ++ks)
        vfA[ni][ks] = *(const bf16x8*)(Vb + (size_t)(w * 128 + ni * 16 + l15) * vstep +
                                       (kv0 + ks * 32 + lg * 8) * 2);
    // ---- QK^T: 32 ds_read + 32 MFMA ----
    {
      f32x4 s0 = {}, s1 = {};
      __builtin_amdgcn_s_setprio(1);
#pragma unroll
      for (int ks = 0; ks < 16; ++ks) {
        const int c = (ks * 64 + lg * 16) ^ kswz;
        bf16x8 kf0 = *(const bf16x8*)(KsR0 + c);
        bf16x8 kf1 = *(const bf16x8*)(KsR1 + c);
        s0 = mfma16(qf[ks], kf0, s0);
        s1 = mfma16(qf[ks], kf1, s1);
      }
      __builtin_amdgcn_s_setprio(0);
#pragma unroll
      for (int r = 0; r < 4; ++r) {
        Ss[(qi * 16 + lg * 4 + r) * 68 + kj * 32 + l15] = s0[r];
        Ss[(qi * 16 + lg * 4 + r) * 68 + kj * 32 + 16 + l15] = s1[r];
      }
    }
    asm volatile("s_waitcnt lgkmcnt(0)" ::: "memory");
    __builtin_amdgcn_s_barrier();

    // ---- phase B: issue K[it+1] stage (window = B+C); softmax ----
    {
      const size_t kvn = (size_t)((it + 1) & (NT - 1)) * 64;
#pragma unroll
      for (int i = 0; i < 16; ++i) {
        const int f = (i * 256 + t) * 16;
        const int row = f >> 10, c = f & 1023;
        gl16(Kb + (kvn + row) * 2048 + (c ^ ((row & 7) << 4)), KsB + f);
      }
      const int row = t >> 3, c8 = t & 7;
      const float* Sr = &Ss[row * 68 + c8 * 8];
      float4 v0 = *(const float4*)(Sr);
      float4 v1 = *(const float4*)(Sr + 4);
      float tmax = fmaxf(fmaxf(fmaxf(v0.x, v0.y), fmaxf(v0.z, v0.w)),
                         fmaxf(fmaxf(v1.x, v1.y), fmaxf(v1.z, v1.w)));
      tmax = fmaxf(tmax, __shfl_xor(tmax, 1));
      tmax = fmaxf(tmax, __shfl_xor(tmax, 2));
      tmax = fmaxf(tmax, __shfl_xor(tmax, 4));
      const float mold = m_s[row];
      const float mnew = fmaxf(mold, tmax);
      const float corr = exp2f(mold - mnew);   // exactly 1.0f when no new max
      const float p0 = exp2f(v0.x - mnew), p1 = exp2f(v0.y - mnew);
      const float p2 = exp2f(v0.z - mnew), p3 = exp2f(v0.w - mnew);
      const float p4 = exp2f(v1.x - mnew), p5 = exp2f(v1.y - mnew);
      const float p6 = exp2f(v1.z - mnew), p7 = exp2f(v1.w - mnew);
      float rsum = ((p0 + p1) + (p2 + p3)) + ((p4 + p5) + (p6 + p7));
      rsum += __shfl_xor(rsum, 1);
      rsum += __shfl_xor(rsum, 2);
      rsum += __shfl_xor(rsum, 4);
      if (c8 == 0) { m_s[row] = mnew; l_s[row] = l_s[row] * corr + rsum; corr_s[row] = corr; }
      const int allskip = __all(corr == 1.0f);
      if (l == 0) flags_s[w] = allskip;
      bf16x8 pb = { (__bf16)p0, (__bf16)p1, (__bf16)p2, (__bf16)p3,
                    (__bf16)p4, (__bf16)p5, (__bf16)p6, (__bf16)p7 };
      *(bf16x8*)((char*)Ps + row * 128 + ((c8 * 16) ^ ((row & 7) << 4))) = pb;
    }
    asm volatile("s_waitcnt lgkmcnt(0)" ::: "memory");
    __builtin_amdgcn_s_barrier();

    // ---- phase C: rescale o; PV (e-lower from vfA, e-upper loaded here) ----
    {
      const int fl = flags_s[0] & flags_s[1] & flags_s[2] & flags_s[3];
      if (!fl) {
#pragma unroll
        for (int mi = 0; mi < 2; ++mi) {
          float cr[4];
#pragma unroll
          for (int r = 0; r < 4; ++r) cr[r] = corr_s[mi * 16 + lg * 4 + r];
#pragma unroll
          for (int ni = 0; ni < 8; ++ni)
#pragma unroll
            for (int r = 0; r < 4; ++r) o[mi][ni][r] *= cr[r];
        }
      }
      bf16x8 pf[2][2];
#pragma unroll
      for (int mi = 0; mi < 2; ++mi)
#pragma unroll
        for (int ks = 0; ks < 2; ++ks)
          pf[mi][ks] = *(const bf16x8*)((const char*)Ps + (mi * 16 + l15) * 128 +
                                        ((ks * 64 + lg * 16) ^ kswz));
      __builtin_amdgcn_s_setprio(1);
#pragma unroll
      for (int ks = 0; ks < 2; ++ks)
#pragma unroll
        for (int ni = 0; ni < 4; ++ni)
#pragma unroll
          for (int mi = 0; mi < 2; ++mi)
            o[mi][ni] = mfma16(pf[mi][ks], vfA[ni][ks], o[mi][ni]);
      __builtin_amdgcn_s_setprio(0);
      bf16x8 vfB[4][2];
#pragma unroll
      for (int ni = 0; ni < 4; ++ni)
#pragma unroll
        for (int ks = 0; ks < 2; ++ks)
          vfB[ni][ks] = *(const bf16x8*)(Vb + (size_t)(w * 128 + 64 + ni * 16 + l15) * vstep +
                                         (kv0 + ks * 32 + lg * 8) * 2);
      __builtin_amdgcn_s_setprio(1);
#pragma unroll
      for (int ks = 0; ks < 2; ++ks)
#pragma unroll
        for (int ni = 0; ni < 4; ++ni)
#pragma unroll
          for (int mi = 0; mi < 2; ++mi)
            o[mi][ni + 4] = mfma16(pf[mi][ks], vfB[ni][ks], o[mi][ni + 4]);
      __builtin_amdgcn_s_setprio(0);
    }
    asm volatile("s_waitcnt vmcnt(0) lgkmcnt(0)" ::: "memory");
    __builtin_amdgcn_s_barrier();
  }

  // ---- epilogue: normalize, write fp32 ----
#pragma unroll
  for (int mi = 0; mi < 2; ++mi) {
    float rl[4];
#pragma unroll
    for (int r = 0; r < 4; ++r) rl[r] = 1.0f / l_s[mi * 16 + lg * 4 + r];
#pragma unroll
    for (int ni = 0; ni < 8; ++ni)
#pragma unroll
      for (int r = 0; r < 4; ++r) {
        const int row = q0 + mi * 16 + lg * 4 + r;
        const int col = w * 128 + ni * 16 + l15;
        Out[((size_t)b * SEQ + row) * DM + col] = o[mi][ni][r] * rl[r];
      }
  }
}

// ---------------------------------------------------------------------------
// Launcher. Workspace (bytes, total 68,681,728):
//   xb 0 | wqkb 16777216 (Wq*SCL;Wk) | wvb 17825792 | qk 18350080
//   ([16384][1024]: Q cols 0..511, K cols 512..1023) | vt 51904512
// ---------------------------------------------------------------------------
extern "C" void kernel_launch(void* const* d_in, const int* in_sizes, int n_in,
                              void* d_out, int out_size, void* d_ws, size_t ws_size,
                              hipStream_t stream) {
  const float* x  = (const float*)d_in[0];
  const float* wq = (const float*)d_in[1];
  const float* wk = (const float*)d_in[2];
  const float* wv = (const float*)d_in[3];
  float* out = (float*)d_out;
  char* ws = (char*)d_ws;

  __bf16* xb   = (__bf16*)(ws);
  __bf16* wqkb = (__bf16*)(ws + 16777216);
  __bf16* wvb  = (__bf16*)(ws + 17825792);
  __bf16* qk   = (__bf16*)(ws + 18350080);
  __bf16* vt   = (__bf16*)(ws + 51904512);

  convert_kernel<<<2048, 256, 0, stream>>>(x, wq, wk, wv,
                                           xb, wqkb, wqkb + 262144, wvb);
  // [Q|K] = x * [Wq*SCL;Wk]^T : [16384x1024]
  gemm_nt_kernel<<<dim3(GS / 128, 1024 / 128), 256, 0, stream>>>(xb, wqkb, qk, 1024);
  // Vt[e][gs] = Wv * x^T : [512x16384]
  gemm_nt_kernel<<<dim3(DM / 128, GS / 128), 256, 0, stream>>>(wvb, xb, vt, GS);
  // fused attention
  attn_kernel<<<512, 256, 0, stream>>>(qk, vt, out);
}